// Round 1
// baseline (17069.525 us; speedup 1.0000x reference)
//
#include <hip/hip_runtime.h>

typedef _Float16 f16;
typedef _Float16 f16x8 __attribute__((ext_vector_type(8)));
typedef float f32x4 __attribute__((ext_vector_type(4)));

#define NSTEPS 512
#define NBATCH 256
#define HID 256
#define KPAD 520            // A-row pitch in f16 (512 + 8 pad -> 2-way LDS aliasing only)
#define NKB 16              // K/32 = 512/32
#define THREADS 512
#define RING_D 64
#define RING_MASK 63

#define WPACK_OFF ((size_t)1024)
#define WPACK_SZB ((size_t)64*16*64*8*2)         // 1 MiB per layer (K padded to 512)
#define RING_OFF (WPACK_OFF + 3*WPACK_SZB)
#define RING_SZB ((size_t)RING_D*NBATCH*HID*2)   // 8 MiB per inter-layer ring
#define WS_NEEDED (RING_OFF + 2*RING_SZB)

__device__ __forceinline__ float sigm(float x){ return 1.f/(1.f+__expf(-x)); }
__device__ __forceinline__ float tanh_f(float x){ return 1.f - 2.f/(1.f+__expf(2.f*x)); }

// ---------------- weight packing: [layer][nt(64)][kb(16)][lane(64)][e(8)] f16 ----
// B-fragment for mfma_f32_16x16x32_f16: col = lane&15, k = (lane>>4)*8 + e.
// Wcat column n (gate row n of torch weight), k<256 -> w_hh[n][k], k>=256 -> w_ih[n][k-256] (0-padded).
__global__ __launch_bounds__(256) void pack_weights(
    const float* __restrict__ wih0, const float* __restrict__ whh0,
    const float* __restrict__ wih1, const float* __restrict__ whh1,
    const float* __restrict__ wih2, const float* __restrict__ whh2,
    unsigned char* __restrict__ ws)
{
  int gid = blockIdx.x*256 + threadIdx.x;
  if (gid >= 3*64*16*64) return;
  int lane  = gid & 63;
  int kb    = (gid>>6) & 15;
  int nt    = (gid>>10) & 63;
  int layer = gid>>16;
  const float* whh = (layer==0)?whh0:((layer==1)?whh1:whh2);
  const float* wih = (layer==0)?wih0:((layer==1)?wih1:wih2);
  int indim = (layer==0)?12:256;
  int n  = nt*16 + (lane&15);
  int k0 = kb*32 + (lane>>4)*8;
  f16x8 v;
  #pragma unroll
  for (int e=0;e<8;++e){
    int k = k0+e;
    float x;
    if (k < HID) x = whh[n*HID + k];
    else { int ki = k-HID; x = (ki<indim)? wih[n*indim+ki] : 0.f; }
    v[e] = (f16)x;
  }
  f16* dst = (f16*)(ws + WPACK_OFF + (size_t)layer*WPACK_SZB)
           + ((size_t)(nt*16+kb)*64 + lane)*8;
  *(f16x8*)dst = v;
}

__device__ __forceinline__ void wait_ge(int* fl, int target){
  int guard = 0;
  while (__hip_atomic_load(fl, __ATOMIC_ACQUIRE, __HIP_MEMORY_SCOPE_AGENT) < target){
    __builtin_amdgcn_s_sleep(2);
    if (++guard > (1<<22)) break;   // bounded: never hang the bench
  }
}

// 48 WGs = 3 layers x 16 batch-groups (16 rows each), persistent over all 512 steps.
__global__ __launch_bounds__(THREADS) void lstm_main(
    const float* __restrict__ input,
    const float* __restrict__ bih0, const float* __restrict__ bhh0,
    const float* __restrict__ bih1, const float* __restrict__ bhh1,
    const float* __restrict__ bih2, const float* __restrict__ bhh2,
    const float* __restrict__ wlin, const float* __restrict__ blin,
    unsigned char* __restrict__ ws, float* __restrict__ out)
{
  __shared__ f16 Ald[16*KPAD];    // A tile: rows=16 batch, k: [0,256) h, [256,512) x
  __shared__ float Lout[16*8];    // layer-2 linear partials

  const int tid  = threadIdx.x;
  const int wid  = tid >> 6;         // 8 waves
  const int lane = tid & 63;
  const int c16  = lane & 15;        // col within 16x16 tile
  const int r0   = (lane >> 4) * 4;  // first of this lane's 4 C rows
  const int bid  = blockIdx.x;
  const int layer= bid >> 4;
  const int grp  = bid & 15;
  const int rowsBase = grp*16;

  int* prodFlags = (int*)ws;          // [layer*16+grp], layers 0,1
  int* consFlags = (int*)(ws + 256);  // [producedLayer*16+grp]

  const f16* __restrict__ wpack = (const f16*)(ws + WPACK_OFF + (size_t)layer*WPACK_SZB);
  f16* ringPrev = (layer>=1)? (f16*)(ws + RING_OFF + (size_t)(layer-1)*RING_SZB) : (f16*)0;
  f16* ringOut  = (layer<=1)? (f16*)(ws + RING_OFF + (size_t)layer*RING_SZB) : (f16*)0;

  // per-lane constants: bias for (gate G, m-tile mi) at this lane's column
  const float* bih = (layer==0)?bih0:((layer==1)?bih1:bih2);
  const float* bhh = (layer==0)?bhh0:((layer==1)?bhh1:bhh2);
  float bias[4][2];
  #pragma unroll
  for (int G=0;G<4;++G)
    #pragma unroll
    for (int mi=0;mi<2;++mi){
      int n = G*256 + (wid + 8*mi)*16 + c16;
      bias[G][mi] = bih[n] + bhh[n];
    }
  float wl[2] = {0.f,0.f}; float bl = 0.f;
  if (layer==2){
    wl[0] = wlin[wid*16 + c16];
    wl[1] = wlin[(wid+8)*16 + c16];
    bl = blin[0];
  }

  for (int i=tid; i<16*KPAD; i+=THREADS) Ald[i] = (f16)0.f;  // h=0, x-pad=0
  float cst[8];
  #pragma unroll
  for (int u=0;u<8;++u) cst[u]=0.f;
  __syncthreads();

  for (int t=0; t<NSTEPS; ++t){
    // ---- staging: x half of A ----
    if (layer==0){
      if (tid < 192){
        int rr = tid/12, ii = tid - rr*12;
        Ald[rr*KPAD + HID + ii] =
            (f16)input[((size_t)t*NBATCH + rowsBase + rr)*12 + ii];
      }
      if ((t&7)==0 && t>=64 && tid==0)                 // ring backpressure
        wait_ge(&consFlags[layer*16+grp], t-56);
    } else {
      if ((t&7)==0){
        wait_ge(&prodFlags[(layer-1)*16+grp], t+8);    // all threads: acquire
        if (layer<2 && t>=64 && tid==0)
          wait_ge(&consFlags[layer*16+grp], t-56);
      }
      const f16* src = ringPrev + ((size_t)(t&RING_MASK)*NBATCH + rowsBase)*HID + tid*8;
      f16x8 v = *(const f16x8*)src;
      *(f16x8*)&Ald[(tid>>5)*KPAD + HID + (tid&31)*8] = v;
    }
    __syncthreads();

    // ---- gates GEMM: wave wid owns hidden tiles m in {wid, wid+8} for all 4 gates ----
    f32x4 acc[4][2];
    #pragma unroll
    for (int G=0;G<4;++G)
      #pragma unroll
      for (int mi=0;mi<2;++mi){ f32x4 z = {0.f,0.f,0.f,0.f}; acc[G][mi]=z; }
    #pragma unroll
    for (int kb=0; kb<NKB; ++kb){
      f16x8 a = *(const f16x8*)&Ald[c16*KPAD + kb*32 + (lane>>4)*8];
      #pragma unroll
      for (int G=0;G<4;++G)
        #pragma unroll
        for (int mi=0;mi<2;++mi){
          int nt = G*16 + 8*mi + wid;
          f16x8 b = *(const f16x8*)(wpack + ((size_t)(nt*16+kb)*64 + lane)*8);
          acc[G][mi] = __builtin_amdgcn_mfma_f32_16x16x32_f16(a, b, acc[G][mi], 0,0,0);
        }
    }

    // ---- LSTM cell, fully in registers (lane holds i,f,g,o for its (4 rows x col)) ----
    float lp[4] = {0.f,0.f,0.f,0.f};
    #pragma unroll
    for (int mi=0;mi<2;++mi){
      int jj = (wid + 8*mi)*16 + c16;
      #pragma unroll
      for (int q=0;q<4;++q){
        float gi = sigm  (acc[0][mi][q] + bias[0][mi]);
        float gf = sigm  (acc[1][mi][q] + bias[1][mi]);
        float gg = tanh_f(acc[2][mi][q] + bias[2][mi]);
        float go = sigm  (acc[3][mi][q] + bias[3][mi]);
        float cv = gf*cst[mi*4+q] + gi*gg;
        cst[mi*4+q] = cv;
        float h  = go * tanh_f(cv);
        Ald[(r0+q)*KPAD + jj] = (f16)h;          // next step's A (h half)
        lp[q] += h * wl[mi];                      // dead for layer<2
      }
    }
    if (layer==2){
      #pragma unroll
      for (int q=0;q<4;++q){
        #pragma unroll
        for (int off=1; off<16; off<<=1) lp[q] += __shfl_xor(lp[q], off);
      }
      if (c16==0){
        #pragma unroll
        for (int q=0;q<4;++q) Lout[(r0+q)*8 + wid] = lp[q];
      }
    }
    __syncthreads();

    if (layer<2){
      // publish h to ring (coalesced from LDS)
      f16x8 v = *(const f16x8*)&Ald[(tid>>5)*KPAD + (tid&31)*8];
      *(f16x8*)(ringOut + ((size_t)(t&RING_MASK)*NBATCH + rowsBase)*HID + tid*8) = v;
      if ((t&7)==7){
        __syncthreads();   // block-uniform condition: legal
        if (tid==0)
          __hip_atomic_store(&prodFlags[layer*16+grp], t+1,
                             __ATOMIC_RELEASE, __HIP_MEMORY_SCOPE_AGENT);
      }
    } else {
      if (tid < 16){
        float s = bl;
        #pragma unroll
        for (int wv=0; wv<8; ++wv) s += Lout[tid*8 + wv];
        out[(size_t)t*NBATCH + rowsBase + tid] = s;
      }
      if ((t&7)==7 && tid==0)
        __hip_atomic_store(&consFlags[(layer-1)*16+grp], t+1,
                           __ATOMIC_RELEASE, __HIP_MEMORY_SCOPE_AGENT);
    }
    // layer-1 consumer progress flag
    if (layer==1 && (t&7)==7 && tid==1)
      __hip_atomic_store(&consFlags[0*16+grp], t+1,
                         __ATOMIC_RELEASE, __HIP_MEMORY_SCOPE_AGENT);
  }
}

extern "C" void kernel_launch(void* const* d_in, const int* in_sizes, int n_in,
                              void* d_out, int out_size, void* d_ws, size_t ws_size,
                              hipStream_t stream)
{
  const float* input=(const float*)d_in[0];
  const float* wih0 =(const float*)d_in[1];
  const float* whh0 =(const float*)d_in[2];
  const float* bih0 =(const float*)d_in[3];
  const float* bhh0 =(const float*)d_in[4];
  const float* wih1 =(const float*)d_in[5];
  const float* whh1 =(const float*)d_in[6];
  const float* bih1 =(const float*)d_in[7];
  const float* bhh1 =(const float*)d_in[8];
  const float* wih2 =(const float*)d_in[9];
  const float* whh2 =(const float*)d_in[10];
  const float* bih2 =(const float*)d_in[11];
  const float* bhh2 =(const float*)d_in[12];
  const float* wlin =(const float*)d_in[13];
  const float* blin =(const float*)d_in[14];
  unsigned char* ws = (unsigned char*)d_ws;
  if (ws_size < WS_NEEDED) return;   // ~19.9 MB needed

  hipMemsetAsync(ws, 0, 1024, stream);  // flags
  hipLaunchKernelGGL(pack_weights, dim3(768), dim3(256), 0, stream,
                     wih0,whh0,wih1,whh1,wih2,whh2, ws);
  hipLaunchKernelGGL(lstm_main, dim3(48), dim3(THREADS), 0, stream,
                     input, bih0,bhh0,bih1,bhh1,bih2,bhh2, wlin, blin,
                     ws, (float*)d_out);
}